// Round 5
// baseline (4163.986 us; speedup 1.0000x reference)
//
#include <hip/hip_runtime.h>
#include <hip/hip_bf16.h>

#define NF   64
#define NH   8
#define ND   8
#define NHID 32

__device__ __forceinline__ float bf2f(unsigned short u) {
    union { unsigned int i; float f; } v; v.i = ((unsigned int)u) << 16; return v.f;
}
__device__ __forceinline__ unsigned short f2bf(float f) {
    __hip_bfloat16 b = __float2bfloat16(f);
    union { __hip_bfloat16 b; unsigned short u; } v; v.b = b; return v.u;
}
__device__ __forceinline__ void unpack8(uint4 u, float* o) {
    o[0] = __uint_as_float(u.x << 16); o[1] = __uint_as_float(u.x & 0xffff0000u);
    o[2] = __uint_as_float(u.y << 16); o[3] = __uint_as_float(u.y & 0xffff0000u);
    o[4] = __uint_as_float(u.z << 16); o[5] = __uint_as_float(u.z & 0xffff0000u);
    o[6] = __uint_as_float(u.w << 16); o[7] = __uint_as_float(u.w & 0xffff0000u);
}
__device__ __forceinline__ uint4 pack8(const float* f) {
    uint4 u;
    u.x = (unsigned)f2bf(f[0]) | ((unsigned)f2bf(f[1]) << 16);
    u.y = (unsigned)f2bf(f[2]) | ((unsigned)f2bf(f[3]) << 16);
    u.z = (unsigned)f2bf(f[4]) | ((unsigned)f2bf(f[5]) << 16);
    u.w = (unsigned)f2bf(f[6]) | ((unsigned)f2bf(f[7]) << 16);
    return u;
}
__device__ __forceinline__ float leaky(float x) { return x > 0.f ? x : 0.2f * x; }
__device__ __forceinline__ float sigmoidf(float x) { return 1.f / (1.f + __expf(-x)); }

// ---------------------------------------------------------------------------
// flags[0]: edge_index stored as int64 (odd 32-bit words of first 32 entries
// all zero). int32 (JAX default x64-disabled coerces int64->int32) -> 0.
// ---------------------------------------------------------------------------
__global__ void detect_kernel(const int* __restrict__ edge, int* __restrict__ flags) {
    if (threadIdx.x == 0 && blockIdx.x == 0) {
        int oddnz = 0;
        for (int i = 0; i < 32; i++) oddnz |= edge[2 * i + 1];
        flags[0] = (oddnz == 0) ? 1 : 0;
    }
}

__device__ __forceinline__ void load_edge(const int* __restrict__ edge, int e, int E,
                                          int wide, int& s, int& d) {
    if (wide) { s = edge[2 * e]; d = edge[2 * (E + e)]; }   // int64: src words [0,2E), dst [2E,4E)
    else      { s = edge[e];     d = edge[E + e]; }          // int32: src [0,E), dst [E,2E)
}

// ---------------------------------------------------------------------------
// Node phase (fp32 in). Stages g_src/g_dst (bf16, ws) and writes the base
// term a_dst * g_dst into d_out (fp32, full overwrite).
// ---------------------------------------------------------------------------
template <bool STORE_G>
__global__ __launch_bounds__(256) void node_kernel_t(
    const float* __restrict__ h,
    const float* __restrict__ W_src, const float* __restrict__ b_src,
    const float* __restrict__ W_dst, const float* __restrict__ b_dst,
    const float* __restrict__ Wa1, const float* __restrict__ ba1,
    const float* __restrict__ Wa2, const float* __restrict__ ba2,
    unsigned short* __restrict__ g_src_out, unsigned short* __restrict__ g_dst_out,
    float* __restrict__ out, int N)
{
    __shared__ __align__(16) float sWs[NF * NF];
    __shared__ __align__(16) float sWd[NF * NF];
    __shared__ __align__(16) float sW1[NF * NHID];
    __shared__ __align__(16) float sW2[NHID * NH];
    __shared__ float sbs[NF], sbd[NF], sb1[NHID], sb2[NH];

    int tid = threadIdx.x;
    for (int i = tid; i < NF * NF; i += 256) { sWs[i] = W_src[i]; sWd[i] = W_dst[i]; }
    for (int i = tid; i < NF * NHID; i += 256) sW1[i] = Wa1[i];
    if (tid < NHID * NH) sW2[tid] = Wa2[tid];
    if (tid < NF) { sbs[tid] = b_src[tid]; sbd[tid] = b_dst[tid]; }
    if (tid < NHID) sb1[tid] = ba1[tid];
    if (tid < NH) sb2[tid] = ba2[tid];
    __syncthreads();

    int n = blockIdx.x * 256 + tid;
    if (n >= N) return;

    float hrow[NF];
    const float4* hv = (const float4*)(h + (size_t)n * NF);
    #pragma unroll
    for (int k = 0; k < 16; k++) {
        float4 u = hv[k];
        hrow[k * 4 + 0] = u.x; hrow[k * 4 + 1] = u.y;
        hrow[k * 4 + 2] = u.z; hrow[k * 4 + 3] = u.w;
    }

    float acc[NF];

    if (STORE_G) {
        #pragma unroll
        for (int j = 0; j < NF; j++) acc[j] = sbs[j];
        for (int i = 0; i < NF; i++) {
            float hi = hrow[i];
            #pragma unroll
            for (int j = 0; j < NF; j++) acc[j] = fmaf(hi, sWs[i * NF + j], acc[j]);
        }
        uint4* gs = (uint4*)(g_src_out + (size_t)n * NF);
        #pragma unroll
        for (int k = 0; k < 8; k++) gs[k] = pack8(acc + k * 8);
    }

    // g_dst kept in acc
    #pragma unroll
    for (int j = 0; j < NF; j++) acc[j] = sbd[j];
    for (int i = 0; i < NF; i++) {
        float hi = hrow[i];
        #pragma unroll
        for (int j = 0; j < NF; j++) acc[j] = fmaf(hi, sWd[i * NF + j], acc[j]);
    }
    if (STORE_G) {
        uint4* gd = (uint4*)(g_dst_out + (size_t)n * NF);
        #pragma unroll
        for (int k = 0; k < 8; k++) gd[k] = pack8(acc + k * 8);
    }

    // dst attention MLP on g_dst
    float x[NF];
    #pragma unroll
    for (int i = 0; i < NF; i++) x[i] = leaky(acc[i]);
    float hid[NHID];
    #pragma unroll
    for (int j = 0; j < NHID; j++) hid[j] = sb1[j];
    for (int i = 0; i < NF; i++) {
        float xi = x[i];
        #pragma unroll
        for (int j = 0; j < NHID; j++) hid[j] = fmaf(xi, sW1[i * NHID + j], hid[j]);
    }
    float a[NH];
    #pragma unroll
    for (int j = 0; j < NH; j++) a[j] = sb2[j];
    #pragma unroll
    for (int k = 0; k < NHID; k++) {
        float xk = leaky(hid[k]);
        #pragma unroll
        for (int j = 0; j < NH; j++) a[j] = fmaf(xk, sW2[k * NH + j], a[j]);
    }
    #pragma unroll
    for (int j = 0; j < NH; j++) a[j] = sigmoidf(a[j]);

    // base term -> fp32 out (full overwrite of the poisoned buffer)
    float4* ap = (float4*)(out + (size_t)n * NF);
    #pragma unroll
    for (int k = 0; k < 16; k++) {
        int j = k * 4;
        ap[k] = make_float4(a[(j + 0) >> 3] * acc[j + 0],
                            a[(j + 1) >> 3] * acc[j + 1],
                            a[(j + 2) >> 3] * acc[j + 2],
                            a[(j + 3) >> 3] * acc[j + 3]);
    }
}

// ---------------------------------------------------------------------------
// Edge phase: staged bf16 g reads, fp32 atomics into d_out.
// ---------------------------------------------------------------------------
__global__ __launch_bounds__(256) void edge_kernel(
    const int* __restrict__ edge, const int* __restrict__ flags,
    const unsigned short* __restrict__ g_src, const unsigned short* __restrict__ g_dst,
    const float* __restrict__ Wa1, const float* __restrict__ ba1,
    const float* __restrict__ Wa2, const float* __restrict__ ba2,
    float* __restrict__ out, int E, int N)
{
    __shared__ __align__(16) float sW1[NF * NHID];
    __shared__ __align__(16) float sW2[NHID * NH];
    __shared__ float sb1[NHID], sb2[NH];
    int tid = threadIdx.x;
    for (int i = tid; i < NF * NHID; i += 256) sW1[i] = Wa1[i];
    if (tid < NHID * NH) sW2[tid] = Wa2[tid];
    if (tid < NHID) sb1[tid] = ba1[tid];
    if (tid < NH) sb2[tid] = ba2[tid];
    __syncthreads();

    int e = blockIdx.x * 256 + tid;
    if (e >= E) return;
    int wide = flags[0];
    int s, d;
    load_edge(edge, e, E, wide, s, d);
    if ((unsigned)s >= (unsigned)N || (unsigned)d >= (unsigned)N) return;

    float ms[NF];
    float hid[NHID];
    #pragma unroll
    for (int j = 0; j < NHID; j++) hid[j] = sb1[j];

    const uint4* gs = (const uint4*)(g_src + (size_t)s * NF);
    const uint4* gd = (const uint4*)(g_dst + (size_t)d * NF);
    #pragma unroll
    for (int k = 0; k < 8; k++) {
        float a8[8], b8[8];
        unpack8(gs[k], a8);
        unpack8(gd[k], b8);
        #pragma unroll
        for (int t = 0; t < 8; t++) {
            int i = k * 8 + t;
            ms[i] = a8[t];
            float x = leaky(a8[t] + b8[t]);
            #pragma unroll
            for (int j = 0; j < NHID; j++) hid[j] = fmaf(x, sW1[i * NHID + j], hid[j]);
        }
    }

    float a[NH];
    #pragma unroll
    for (int j = 0; j < NH; j++) a[j] = sb2[j];
    #pragma unroll
    for (int k = 0; k < NHID; k++) {
        float xk = leaky(hid[k]);
        #pragma unroll
        for (int j = 0; j < NH; j++) a[j] = fmaf(xk, sW2[k * NH + j], a[j]);
    }

    float* arow = out + (size_t)d * NF;
    #pragma unroll
    for (int hh = 0; hh < NH; hh++) {
        float ah = sigmoidf(a[hh]);
        #pragma unroll
        for (int dd = 0; dd < ND; dd++)
            unsafeAtomicAdd(arow + hh * ND + dd, ah * ms[hh * ND + dd]);
    }
}

// ---------------------------------------------------------------------------
// Zero-ws fallback: fused edge kernel recomputing g rows per edge (fp32 out).
// ---------------------------------------------------------------------------
__global__ __launch_bounds__(256) void edge_kernel_fused(
    const int* __restrict__ edge, const int* __restrict__ flags,
    const float* __restrict__ h,
    const float* __restrict__ W_src, const float* __restrict__ b_src,
    const float* __restrict__ W_dst, const float* __restrict__ b_dst,
    const float* __restrict__ Wa1, const float* __restrict__ ba1,
    const float* __restrict__ Wa2, const float* __restrict__ ba2,
    float* __restrict__ out, int E, int N)
{
    __shared__ __align__(16) float sWs[NF * NF];
    __shared__ __align__(16) float sWd[NF * NF];
    __shared__ __align__(16) float sW1[NF * NHID];
    __shared__ __align__(16) float sW2[NHID * NH];
    __shared__ float sbs[NF], sbd[NF], sb1[NHID], sb2[NH];
    int tid = threadIdx.x;
    for (int i = tid; i < NF * NF; i += 256) { sWs[i] = W_src[i]; sWd[i] = W_dst[i]; }
    for (int i = tid; i < NF * NHID; i += 256) sW1[i] = Wa1[i];
    if (tid < NHID * NH) sW2[tid] = Wa2[tid];
    if (tid < NF) { sbs[tid] = b_src[tid]; sbd[tid] = b_dst[tid]; }
    if (tid < NHID) sb1[tid] = ba1[tid];
    if (tid < NH) sb2[tid] = ba2[tid];
    __syncthreads();

    int e = blockIdx.x * 256 + tid;
    if (e >= E) return;
    int wide = flags ? flags[0] : 0;
    int s, d;
    load_edge(edge, e, E, wide, s, d);
    if ((unsigned)s >= (unsigned)N || (unsigned)d >= (unsigned)N) return;

    float gs[NF], msg[NF];
    {
        float hrow[NF];
        #pragma unroll
        for (int i = 0; i < NF; i++) hrow[i] = h[(size_t)s * NF + i];
        #pragma unroll
        for (int j = 0; j < NF; j++) gs[j] = sbs[j];
        for (int i = 0; i < NF; i++) {
            float hi = hrow[i];
            #pragma unroll
            for (int j = 0; j < NF; j++) gs[j] = fmaf(hi, sWs[i * NF + j], gs[j]);
        }
    }
    #pragma unroll
    for (int j = 0; j < NF; j++) msg[j] = gs[j] + sbd[j];
    for (int i = 0; i < NF; i++) {
        float hi = h[(size_t)d * NF + i];
        #pragma unroll
        for (int j = 0; j < NF; j++) msg[j] = fmaf(hi, sWd[i * NF + j], msg[j]);
    }

    float hid[NHID];
    #pragma unroll
    for (int j = 0; j < NHID; j++) hid[j] = sb1[j];
    for (int i = 0; i < NF; i++) {
        float x = leaky(msg[i]);
        #pragma unroll
        for (int j = 0; j < NHID; j++) hid[j] = fmaf(x, sW1[i * NHID + j], hid[j]);
    }
    float a[NH];
    #pragma unroll
    for (int j = 0; j < NH; j++) a[j] = sb2[j];
    #pragma unroll
    for (int k = 0; k < NHID; k++) {
        float xk = leaky(hid[k]);
        #pragma unroll
        for (int j = 0; j < NH; j++) a[j] = fmaf(xk, sW2[k * NH + j], a[j]);
    }

    float* arow = out + (size_t)d * NF;
    #pragma unroll
    for (int hh = 0; hh < NH; hh++) {
        float ah = sigmoidf(a[hh]);
        #pragma unroll
        for (int dd = 0; dd < ND; dd++)
            unsafeAtomicAdd(arow + hh * ND + dd, ah * gs[hh * ND + dd]);
    }
}

extern "C" void kernel_launch(void* const* d_in, const int* in_sizes, int n_in,
                              void* d_out, int out_size, void* d_ws, size_t ws_size,
                              hipStream_t stream) {
    const float* h       = (const float*)d_in[0];
    const float* W_src   = (const float*)d_in[1];
    const float* b_src   = (const float*)d_in[2];
    const float* W_dst   = (const float*)d_in[3];
    const float* b_dst   = (const float*)d_in[4];
    const float* Wa1_src = (const float*)d_in[5];
    const float* ba1_src = (const float*)d_in[6];
    const float* Wa2_src = (const float*)d_in[7];
    const float* ba2_src = (const float*)d_in[8];
    const float* Wa1_dst = (const float*)d_in[9];
    const float* ba1_dst = (const float*)d_in[10];
    const float* Wa2_dst = (const float*)d_in[11];
    const float* ba2_dst = (const float*)d_in[12];
    const int* edge = (const int*)d_in[13];

    int N = in_sizes[0] / NF;
    int E = in_sizes[13] / 2;
    float* out = (float*)d_out;

    const size_t FLAG_BYTES = 256;
    size_t gB = (size_t)N * NF * sizeof(unsigned short);

    int nodeBlocks = (N + 255) / 256;
    int edgeBlocks = (E + 255) / 256;

    if (ws_size >= FLAG_BYTES + 2 * gB) {
        int* flags = (int*)d_ws;
        unsigned short* g_src = (unsigned short*)((char*)d_ws + FLAG_BYTES);
        unsigned short* g_dst = g_src + (size_t)N * NF;

        detect_kernel<<<1, 1, 0, stream>>>(edge, flags);

        node_kernel_t<true><<<nodeBlocks, 256, 0, stream>>>(
            h, W_src, b_src, W_dst, b_dst,
            Wa1_dst, ba1_dst, Wa2_dst, ba2_dst,
            g_src, g_dst, out, N);

        edge_kernel<<<edgeBlocks, 256, 0, stream>>>(
            edge, flags, g_src, g_dst,
            Wa1_src, ba1_src, Wa2_src, ba2_src,
            out, E, N);
    } else if (ws_size >= FLAG_BYTES) {
        int* flags = (int*)d_ws;
        detect_kernel<<<1, 1, 0, stream>>>(edge, flags);

        node_kernel_t<false><<<nodeBlocks, 256, 0, stream>>>(
            h, W_src, b_src, W_dst, b_dst,
            Wa1_dst, ba1_dst, Wa2_dst, ba2_dst,
            nullptr, nullptr, out, N);

        edge_kernel_fused<<<edgeBlocks, 256, 0, stream>>>(
            edge, flags, h,
            W_src, b_src, W_dst, b_dst,
            Wa1_src, ba1_src, Wa2_src, ba2_src,
            out, E, N);
    } else {
        node_kernel_t<false><<<nodeBlocks, 256, 0, stream>>>(
            h, W_src, b_src, W_dst, b_dst,
            Wa1_dst, ba1_dst, Wa2_dst, ba2_dst,
            nullptr, nullptr, out, N);

        edge_kernel_fused<<<edgeBlocks, 256, 0, stream>>>(
            edge, nullptr, h,
            W_src, b_src, W_dst, b_dst,
            Wa1_src, ba1_src, Wa2_src, ba2_src,
            out, E, N);
    }
}

// Round 6
// 557.477 us; speedup vs baseline: 7.4693x; 7.4693x over previous
//
#include <hip/hip_runtime.h>
#include <hip/hip_bf16.h>
#include <hip/hip_fp16.h>

#define NF   64
#define NH   8
#define ND   8
#define NHID 32

__device__ __forceinline__ float bf2f(unsigned short u) {
    union { unsigned int i; float f; } v; v.i = ((unsigned int)u) << 16; return v.f;
}
__device__ __forceinline__ unsigned short f2bf(float f) {
    __hip_bfloat16 b = __float2bfloat16(f);
    union { __hip_bfloat16 b; unsigned short u; } v; v.b = b; return v.u;
}
__device__ __forceinline__ void unpack8(uint4 u, float* o) {
    o[0] = __uint_as_float(u.x << 16); o[1] = __uint_as_float(u.x & 0xffff0000u);
    o[2] = __uint_as_float(u.y << 16); o[3] = __uint_as_float(u.y & 0xffff0000u);
    o[4] = __uint_as_float(u.z << 16); o[5] = __uint_as_float(u.z & 0xffff0000u);
    o[6] = __uint_as_float(u.w << 16); o[7] = __uint_as_float(u.w & 0xffff0000u);
}
__device__ __forceinline__ uint4 pack8(const float* f) {
    uint4 u;
    u.x = (unsigned)f2bf(f[0]) | ((unsigned)f2bf(f[1]) << 16);
    u.y = (unsigned)f2bf(f[2]) | ((unsigned)f2bf(f[3]) << 16);
    u.z = (unsigned)f2bf(f[4]) | ((unsigned)f2bf(f[5]) << 16);
    u.w = (unsigned)f2bf(f[6]) | ((unsigned)f2bf(f[7]) << 16);
    return u;
}
__device__ __forceinline__ float leaky(float x) { return x > 0.f ? x : 0.2f * x; }
__device__ __forceinline__ float sigmoidf(float x) { return 1.f / (1.f + __expf(-x)); }

__global__ void detect_kernel(const int* __restrict__ edge, int* __restrict__ flags) {
    if (threadIdx.x == 0 && blockIdx.x == 0) {
        int oddnz = 0;
        for (int i = 0; i < 32; i++) oddnz |= edge[2 * i + 1];
        flags[0] = (oddnz == 0) ? 1 : 0;
    }
}

__device__ __forceinline__ void load_edge(const int* __restrict__ edge, int e, int E,
                                          int wide, int& s, int& d) {
    if (wide) { s = edge[2 * e]; d = edge[2 * (E + e)]; }   // int64 storage
    else      { s = edge[e];     d = edge[E + e]; }          // int32 storage
}

// ---------------------------------------------------------------------------
// Node phase: stages g_src/g_dst (bf16), writes base a_dst*g_dst into fp32
// out (full overwrite), and zeroes counts/cursor for the sort path.
// ---------------------------------------------------------------------------
template <bool STORE_G>
__global__ __launch_bounds__(256) void node_kernel_t(
    const float* __restrict__ h,
    const float* __restrict__ W_src, const float* __restrict__ b_src,
    const float* __restrict__ W_dst, const float* __restrict__ b_dst,
    const float* __restrict__ Wa1, const float* __restrict__ ba1,
    const float* __restrict__ Wa2, const float* __restrict__ ba2,
    unsigned short* __restrict__ g_src_out, unsigned short* __restrict__ g_dst_out,
    float* __restrict__ out, int* __restrict__ counts, int* __restrict__ cursor, int N)
{
    __shared__ __align__(16) float sWs[NF * NF];
    __shared__ __align__(16) float sWd[NF * NF];
    __shared__ __align__(16) float sW1[NF * NHID];
    __shared__ __align__(16) float sW2[NHID * NH];
    __shared__ float sbs[NF], sbd[NF], sb1[NHID], sb2[NH];

    int tid = threadIdx.x;
    for (int i = tid; i < NF * NF; i += 256) { sWs[i] = W_src[i]; sWd[i] = W_dst[i]; }
    for (int i = tid; i < NF * NHID; i += 256) sW1[i] = Wa1[i];
    if (tid < NHID * NH) sW2[tid] = Wa2[tid];
    if (tid < NF) { sbs[tid] = b_src[tid]; sbd[tid] = b_dst[tid]; }
    if (tid < NHID) sb1[tid] = ba1[tid];
    if (tid < NH) sb2[tid] = ba2[tid];
    __syncthreads();

    int n = blockIdx.x * 256 + tid;
    if (n >= N) return;

    if (counts) { counts[n] = 0; cursor[n] = 0; }

    float hrow[NF];
    const float4* hv = (const float4*)(h + (size_t)n * NF);
    #pragma unroll
    for (int k = 0; k < 16; k++) {
        float4 u = hv[k];
        hrow[k * 4 + 0] = u.x; hrow[k * 4 + 1] = u.y;
        hrow[k * 4 + 2] = u.z; hrow[k * 4 + 3] = u.w;
    }

    float acc[NF];
    const float4* Wsv = (const float4*)sWs;
    const float4* Wdv = (const float4*)sWd;

    if (STORE_G) {
        #pragma unroll
        for (int j = 0; j < NF; j++) acc[j] = sbs[j];
        for (int i = 0; i < NF; i++) {
            float hi = hrow[i];
            #pragma unroll
            for (int jb = 0; jb < 16; jb++) {
                float4 w = Wsv[i * 16 + jb];
                acc[jb * 4 + 0] = fmaf(hi, w.x, acc[jb * 4 + 0]);
                acc[jb * 4 + 1] = fmaf(hi, w.y, acc[jb * 4 + 1]);
                acc[jb * 4 + 2] = fmaf(hi, w.z, acc[jb * 4 + 2]);
                acc[jb * 4 + 3] = fmaf(hi, w.w, acc[jb * 4 + 3]);
            }
        }
        uint4* gs = (uint4*)(g_src_out + (size_t)n * NF);
        #pragma unroll
        for (int k = 0; k < 8; k++) gs[k] = pack8(acc + k * 8);
    }

    // g_dst in acc
    #pragma unroll
    for (int j = 0; j < NF; j++) acc[j] = sbd[j];
    for (int i = 0; i < NF; i++) {
        float hi = hrow[i];
        #pragma unroll
        for (int jb = 0; jb < 16; jb++) {
            float4 w = Wdv[i * 16 + jb];
            acc[jb * 4 + 0] = fmaf(hi, w.x, acc[jb * 4 + 0]);
            acc[jb * 4 + 1] = fmaf(hi, w.y, acc[jb * 4 + 1]);
            acc[jb * 4 + 2] = fmaf(hi, w.z, acc[jb * 4 + 2]);
            acc[jb * 4 + 3] = fmaf(hi, w.w, acc[jb * 4 + 3]);
        }
    }
    if (STORE_G) {
        uint4* gd = (uint4*)(g_dst_out + (size_t)n * NF);
        #pragma unroll
        for (int k = 0; k < 8; k++) gd[k] = pack8(acc + k * 8);
    }

    // dst attention MLP
    float hid[NHID];
    #pragma unroll
    for (int j = 0; j < NHID; j++) hid[j] = sb1[j];
    const float4* W1v = (const float4*)sW1;
    for (int i = 0; i < NF; i++) {
        float xi = leaky(acc[i]);
        #pragma unroll
        for (int jb = 0; jb < 8; jb++) {
            float4 w = W1v[i * 8 + jb];
            hid[jb * 4 + 0] = fmaf(xi, w.x, hid[jb * 4 + 0]);
            hid[jb * 4 + 1] = fmaf(xi, w.y, hid[jb * 4 + 1]);
            hid[jb * 4 + 2] = fmaf(xi, w.z, hid[jb * 4 + 2]);
            hid[jb * 4 + 3] = fmaf(xi, w.w, hid[jb * 4 + 3]);
        }
    }
    float a[NH];
    #pragma unroll
    for (int j = 0; j < NH; j++) a[j] = sb2[j];
    #pragma unroll
    for (int k = 0; k < NHID; k++) {
        float xk = leaky(hid[k]);
        #pragma unroll
        for (int j = 0; j < NH; j++) a[j] = fmaf(xk, sW2[k * NH + j], a[j]);
    }
    #pragma unroll
    for (int j = 0; j < NH; j++) a[j] = sigmoidf(a[j]);

    float4* ap = (float4*)(out + (size_t)n * NF);
    #pragma unroll
    for (int k = 0; k < 16; k++) {
        int j = k * 4;
        ap[k] = make_float4(a[(j + 0) >> 3] * acc[j + 0],
                            a[(j + 1) >> 3] * acc[j + 1],
                            a[(j + 2) >> 3] * acc[j + 2],
                            a[(j + 3) >> 3] * acc[j + 3]);
    }
}

// ---------------------------------------------------------------------------
// Edge MLP: per edge compute 8 attention sigmoids -> fp16x8 (16B store),
// plus histogram of dst. NO per-feature atomics.
// ---------------------------------------------------------------------------
__global__ __launch_bounds__(256) void edge_mlp_kernel(
    const int* __restrict__ edge, const int* __restrict__ flags,
    const unsigned short* __restrict__ g_src, const unsigned short* __restrict__ g_dst,
    const float* __restrict__ Wa1, const float* __restrict__ ba1,
    const float* __restrict__ Wa2, const float* __restrict__ ba2,
    __half* __restrict__ a_edge, int* __restrict__ counts, int E, int N)
{
    __shared__ __align__(16) float sW1[NF * NHID];
    __shared__ __align__(16) float sW2[NHID * NH];
    __shared__ float sb1[NHID], sb2[NH];
    int tid = threadIdx.x;
    for (int i = tid; i < NF * NHID; i += 256) sW1[i] = Wa1[i];
    if (tid < NHID * NH) sW2[tid] = Wa2[tid];
    if (tid < NHID) sb1[tid] = ba1[tid];
    if (tid < NH) sb2[tid] = ba2[tid];
    __syncthreads();

    int e = blockIdx.x * 256 + tid;
    if (e >= E) return;
    int s, d;
    load_edge(edge, e, E, flags[0], s, d);
    if ((unsigned)s >= (unsigned)N || (unsigned)d >= (unsigned)N) return;

    float hid[NHID];
    #pragma unroll
    for (int j = 0; j < NHID; j++) hid[j] = sb1[j];

    const uint4* gs = (const uint4*)(g_src + (size_t)s * NF);
    const uint4* gd = (const uint4*)(g_dst + (size_t)d * NF);
    const float4* W1v = (const float4*)sW1;
    #pragma unroll
    for (int k = 0; k < 8; k++) {
        float a8[8], b8[8];
        unpack8(gs[k], a8);
        unpack8(gd[k], b8);
        #pragma unroll
        for (int t = 0; t < 8; t++) {
            int i = k * 8 + t;
            float x = leaky(a8[t] + b8[t]);
            #pragma unroll
            for (int jb = 0; jb < 8; jb++) {
                float4 w = W1v[i * 8 + jb];
                hid[jb * 4 + 0] = fmaf(x, w.x, hid[jb * 4 + 0]);
                hid[jb * 4 + 1] = fmaf(x, w.y, hid[jb * 4 + 1]);
                hid[jb * 4 + 2] = fmaf(x, w.z, hid[jb * 4 + 2]);
                hid[jb * 4 + 3] = fmaf(x, w.w, hid[jb * 4 + 3]);
            }
        }
    }

    float a[NH];
    #pragma unroll
    for (int j = 0; j < NH; j++) a[j] = sb2[j];
    #pragma unroll
    for (int k = 0; k < NHID; k++) {
        float xk = leaky(hid[k]);
        #pragma unroll
        for (int j = 0; j < NH; j++) a[j] = fmaf(xk, sW2[k * NH + j], a[j]);
    }

    atomicAdd(&counts[d], 1);

    union { __half h[8]; uint4 u; } pk;
    #pragma unroll
    for (int j = 0; j < NH; j++) pk.h[j] = __float2half(sigmoidf(a[j]));
    *(uint4*)(a_edge + (size_t)e * NH) = pk.u;
}

// ---------------------------------------------------------------------------
// Exclusive-scan machinery (counts -> CSR offsets), 2048 elems per block.
// ---------------------------------------------------------------------------
__global__ __launch_bounds__(256) void scan1_kernel(
    const int* __restrict__ counts, int* __restrict__ offsets,
    int* __restrict__ bsums, int N)
{
    __shared__ int lds[256];
    int tid = threadIdx.x;
    int base = blockIdx.x * 2048 + tid * 8;
    int v[8]; int s = 0;
    #pragma unroll
    for (int k = 0; k < 8; k++) { int idx = base + k; int t = (idx < N) ? counts[idx] : 0; v[k] = t; s += t; }
    lds[tid] = s;
    __syncthreads();
    for (int off = 1; off < 256; off <<= 1) {
        int y = (tid >= off) ? lds[tid - off] : 0;
        __syncthreads();
        lds[tid] += y;
        __syncthreads();
    }
    int run = lds[tid] - s;   // exclusive prefix of this thread
    #pragma unroll
    for (int k = 0; k < 8; k++) { int idx = base + k; if (idx < N) offsets[idx] = run; run += v[k]; }
    if (tid == 255) bsums[blockIdx.x] = lds[255];
}

__global__ void scan2_kernel(int* __restrict__ bsums, int* __restrict__ offsets, int NB, int N) {
    if (threadIdx.x == 0 && blockIdx.x == 0) {
        int run = 0;
        for (int i = 0; i < NB; i++) { int t = bsums[i]; bsums[i] = run; run += t; }
        offsets[N] = run;
    }
}

__global__ __launch_bounds__(256) void scan3_kernel(
    int* __restrict__ offsets, const int* __restrict__ bsums, int N)
{
    int add = bsums[blockIdx.x];
    int base = blockIdx.x * 2048 + threadIdx.x * 8;
    #pragma unroll
    for (int k = 0; k < 8; k++) { int idx = base + k; if (idx < N) offsets[idx] += add; }
}

__global__ __launch_bounds__(256) void scatter_kernel(
    const int* __restrict__ edge, const int* __restrict__ flags,
    const int* __restrict__ offsets, int* __restrict__ cursor,
    uint2* __restrict__ sorted_se, int E, int N)
{
    int e = blockIdx.x * 256 + threadIdx.x;
    if (e >= E) return;
    int s, d;
    load_edge(edge, e, E, flags[0], s, d);
    if ((unsigned)s >= (unsigned)N || (unsigned)d >= (unsigned)N) return;
    int pos = offsets[d] + atomicAdd(&cursor[d], 1);
    sorted_se[pos] = make_uint2((unsigned)s, (unsigned)e);
}

// ---------------------------------------------------------------------------
// Aggregate: one wave per dst, lane = feature. No atomics.
// ---------------------------------------------------------------------------
__global__ __launch_bounds__(256) void aggregate_kernel(
    const int* __restrict__ offsets, const uint2* __restrict__ sorted_se,
    const __half* __restrict__ a_edge, const unsigned short* __restrict__ g_src,
    float* __restrict__ out, int N)
{
    int d = blockIdx.x * 4 + (threadIdx.x >> 6);
    if (d >= N) return;
    int j = threadIdx.x & 63;
    int beg = offsets[d], end = offsets[d + 1];
    float acc = 0.f;
    for (int i = beg; i < end; i++) {
        uint2 se = sorted_se[i];
        float av = __half2float(a_edge[(size_t)se.y * NH + (j >> 3)]);
        float gv = bf2f(g_src[(size_t)se.x * NF + j]);
        acc = fmaf(av, gv, acc);
    }
    out[(size_t)d * NF + j] += acc;
}

// ---------------------------------------------------------------------------
// Fallback: R5's atomic edge kernel (known-good path if ws is small).
// ---------------------------------------------------------------------------
__global__ __launch_bounds__(256) void edge_kernel(
    const int* __restrict__ edge, const int* __restrict__ flags,
    const unsigned short* __restrict__ g_src, const unsigned short* __restrict__ g_dst,
    const float* __restrict__ Wa1, const float* __restrict__ ba1,
    const float* __restrict__ Wa2, const float* __restrict__ ba2,
    float* __restrict__ out, int E, int N)
{
    __shared__ __align__(16) float sW1[NF * NHID];
    __shared__ __align__(16) float sW2[NHID * NH];
    __shared__ float sb1[NHID], sb2[NH];
    int tid = threadIdx.x;
    for (int i = tid; i < NF * NHID; i += 256) sW1[i] = Wa1[i];
    if (tid < NHID * NH) sW2[tid] = Wa2[tid];
    if (tid < NHID) sb1[tid] = ba1[tid];
    if (tid < NH) sb2[tid] = ba2[tid];
    __syncthreads();

    int e = blockIdx.x * 256 + tid;
    if (e >= E) return;
    int s, d;
    load_edge(edge, e, E, flags[0], s, d);
    if ((unsigned)s >= (unsigned)N || (unsigned)d >= (unsigned)N) return;

    float ms[NF];
    float hid[NHID];
    #pragma unroll
    for (int j = 0; j < NHID; j++) hid[j] = sb1[j];

    const uint4* gs = (const uint4*)(g_src + (size_t)s * NF);
    const uint4* gd = (const uint4*)(g_dst + (size_t)d * NF);
    #pragma unroll
    for (int k = 0; k < 8; k++) {
        float a8[8], b8[8];
        unpack8(gs[k], a8);
        unpack8(gd[k], b8);
        #pragma unroll
        for (int t = 0; t < 8; t++) {
            int i = k * 8 + t;
            ms[i] = a8[t];
            float x = leaky(a8[t] + b8[t]);
            #pragma unroll
            for (int j = 0; j < NHID; j++) hid[j] = fmaf(x, sW1[i * NHID + j], hid[j]);
        }
    }

    float a[NH];
    #pragma unroll
    for (int j = 0; j < NH; j++) a[j] = sb2[j];
    #pragma unroll
    for (int k = 0; k < NHID; k++) {
        float xk = leaky(hid[k]);
        #pragma unroll
        for (int j = 0; j < NH; j++) a[j] = fmaf(xk, sW2[k * NH + j], a[j]);
    }

    float* arow = out + (size_t)d * NF;
    #pragma unroll
    for (int hh = 0; hh < NH; hh++) {
        float ah = sigmoidf(a[hh]);
        #pragma unroll
        for (int dd = 0; dd < ND; dd++)
            unsafeAtomicAdd(arow + hh * ND + dd, ah * ms[hh * ND + dd]);
    }
}

__global__ __launch_bounds__(256) void edge_kernel_fused(
    const int* __restrict__ edge, const int* __restrict__ flags,
    const float* __restrict__ h,
    const float* __restrict__ W_src, const float* __restrict__ b_src,
    const float* __restrict__ W_dst, const float* __restrict__ b_dst,
    const float* __restrict__ Wa1, const float* __restrict__ ba1,
    const float* __restrict__ Wa2, const float* __restrict__ ba2,
    float* __restrict__ out, int E, int N)
{
    __shared__ __align__(16) float sWs[NF * NF];
    __shared__ __align__(16) float sWd[NF * NF];
    __shared__ __align__(16) float sW1[NF * NHID];
    __shared__ __align__(16) float sW2[NHID * NH];
    __shared__ float sbs[NF], sbd[NF], sb1[NHID], sb2[NH];
    int tid = threadIdx.x;
    for (int i = tid; i < NF * NF; i += 256) { sWs[i] = W_src[i]; sWd[i] = W_dst[i]; }
    for (int i = tid; i < NF * NHID; i += 256) sW1[i] = Wa1[i];
    if (tid < NHID * NH) sW2[tid] = Wa2[tid];
    if (tid < NF) { sbs[tid] = b_src[tid]; sbd[tid] = b_dst[tid]; }
    if (tid < NHID) sb1[tid] = ba1[tid];
    if (tid < NH) sb2[tid] = ba2[tid];
    __syncthreads();

    int e = blockIdx.x * 256 + tid;
    if (e >= E) return;
    int wide = flags ? flags[0] : 0;
    int s, d;
    load_edge(edge, e, E, wide, s, d);
    if ((unsigned)s >= (unsigned)N || (unsigned)d >= (unsigned)N) return;

    float gsr[NF], msg[NF];
    {
        float hrow[NF];
        #pragma unroll
        for (int i = 0; i < NF; i++) hrow[i] = h[(size_t)s * NF + i];
        #pragma unroll
        for (int j = 0; j < NF; j++) gsr[j] = sbs[j];
        for (int i = 0; i < NF; i++) {
            float hi = hrow[i];
            #pragma unroll
            for (int j = 0; j < NF; j++) gsr[j] = fmaf(hi, sWs[i * NF + j], gsr[j]);
        }
    }
    #pragma unroll
    for (int j = 0; j < NF; j++) msg[j] = gsr[j] + sbd[j];
    for (int i = 0; i < NF; i++) {
        float hi = h[(size_t)d * NF + i];
        #pragma unroll
        for (int j = 0; j < NF; j++) msg[j] = fmaf(hi, sWd[i * NF + j], msg[j]);
    }

    float hid[NHID];
    #pragma unroll
    for (int j = 0; j < NHID; j++) hid[j] = sb1[j];
    for (int i = 0; i < NF; i++) {
        float x = leaky(msg[i]);
        #pragma unroll
        for (int j = 0; j < NHID; j++) hid[j] = fmaf(x, sW1[i * NHID + j], hid[j]);
    }
    float a[NH];
    #pragma unroll
    for (int j = 0; j < NH; j++) a[j] = sb2[j];
    #pragma unroll
    for (int k = 0; k < NHID; k++) {
        float xk = leaky(hid[k]);
        #pragma unroll
        for (int j = 0; j < NH; j++) a[j] = fmaf(xk, sW2[k * NH + j], a[j]);
    }

    float* arow = out + (size_t)d * NF;
    #pragma unroll
    for (int hh = 0; hh < NH; hh++) {
        float ah = sigmoidf(a[hh]);
        #pragma unroll
        for (int dd = 0; dd < ND; dd++)
            unsafeAtomicAdd(arow + hh * ND + dd, ah * gsr[hh * ND + dd]);
    }
}

static inline size_t al256(size_t x) { return (x + 255) & ~(size_t)255; }

extern "C" void kernel_launch(void* const* d_in, const int* in_sizes, int n_in,
                              void* d_out, int out_size, void* d_ws, size_t ws_size,
                              hipStream_t stream) {
    const float* h       = (const float*)d_in[0];
    const float* W_src   = (const float*)d_in[1];
    const float* b_src   = (const float*)d_in[2];
    const float* W_dst   = (const float*)d_in[3];
    const float* b_dst   = (const float*)d_in[4];
    const float* Wa1_src = (const float*)d_in[5];
    const float* ba1_src = (const float*)d_in[6];
    const float* Wa2_src = (const float*)d_in[7];
    const float* ba2_src = (const float*)d_in[8];
    const float* Wa1_dst = (const float*)d_in[9];
    const float* ba1_dst = (const float*)d_in[10];
    const float* Wa2_dst = (const float*)d_in[11];
    const float* ba2_dst = (const float*)d_in[12];
    const int* edge = (const int*)d_in[13];

    int N = in_sizes[0] / NF;
    int E = in_sizes[13] / 2;
    float* out = (float*)d_out;

    int nodeBlocks = (N + 255) / 256;
    int edgeBlocks = (E + 255) / 256;
    int NB1 = (N + 2047) / 2048;

    // ws layout (sort path)
    size_t o_flags  = 0;
    size_t o_gsrc   = al256(o_flags + 256);
    size_t o_gdst   = al256(o_gsrc + (size_t)N * NF * 2);
    size_t o_aedge  = al256(o_gdst + (size_t)N * NF * 2);
    size_t o_counts = al256(o_aedge + (size_t)E * NH * 2);
    size_t o_offs   = al256(o_counts + (size_t)N * 4);
    size_t o_cursor = al256(o_offs + ((size_t)N + 1) * 4);
    size_t o_bsums  = al256(o_cursor + (size_t)N * 4);
    size_t o_sorted = al256(o_bsums + (size_t)NB1 * 4);
    size_t need     = o_sorted + (size_t)E * 8;

    size_t gB = (size_t)N * NF * 2;

    if (ws_size >= need) {
        // ---------------- Sort-based path (no per-feature atomics) ----------
        char* w = (char*)d_ws;
        int*            flags   = (int*)(w + o_flags);
        unsigned short* g_src   = (unsigned short*)(w + o_gsrc);
        unsigned short* g_dst   = (unsigned short*)(w + o_gdst);
        __half*         a_edge  = (__half*)(w + o_aedge);
        int*            counts  = (int*)(w + o_counts);
        int*            offsets = (int*)(w + o_offs);
        int*            cursor  = (int*)(w + o_cursor);
        int*            bsums   = (int*)(w + o_bsums);
        uint2*          sorted  = (uint2*)(w + o_sorted);

        detect_kernel<<<1, 1, 0, stream>>>(edge, flags);

        node_kernel_t<true><<<nodeBlocks, 256, 0, stream>>>(
            h, W_src, b_src, W_dst, b_dst,
            Wa1_dst, ba1_dst, Wa2_dst, ba2_dst,
            g_src, g_dst, out, counts, cursor, N);

        edge_mlp_kernel<<<edgeBlocks, 256, 0, stream>>>(
            edge, flags, g_src, g_dst,
            Wa1_src, ba1_src, Wa2_src, ba2_src,
            a_edge, counts, E, N);

        scan1_kernel<<<NB1, 256, 0, stream>>>(counts, offsets, bsums, N);
        scan2_kernel<<<1, 1, 0, stream>>>(bsums, offsets, NB1, N);
        scan3_kernel<<<NB1, 256, 0, stream>>>(offsets, bsums, N);

        scatter_kernel<<<edgeBlocks, 256, 0, stream>>>(
            edge, flags, offsets, cursor, sorted, E, N);

        aggregate_kernel<<<(N + 3) / 4, 256, 0, stream>>>(
            offsets, sorted, a_edge, g_src, out, N);
    } else if (ws_size >= 256 + 2 * gB) {
        // ---------------- R5 known-good path (scattered fp32 atomics) ------
        int* flags = (int*)d_ws;
        unsigned short* g_src = (unsigned short*)((char*)d_ws + 256);
        unsigned short* g_dst = g_src + (size_t)N * NF;

        detect_kernel<<<1, 1, 0, stream>>>(edge, flags);

        node_kernel_t<true><<<nodeBlocks, 256, 0, stream>>>(
            h, W_src, b_src, W_dst, b_dst,
            Wa1_dst, ba1_dst, Wa2_dst, ba2_dst,
            g_src, g_dst, out, nullptr, nullptr, N);

        edge_kernel<<<edgeBlocks, 256, 0, stream>>>(
            edge, flags, g_src, g_dst,
            Wa1_src, ba1_src, Wa2_src, ba2_src,
            out, E, N);
    } else {
        // ---------------- zero-ws fused fallback ---------------------------
        int* flags = (ws_size >= 256) ? (int*)d_ws : nullptr;
        if (flags) detect_kernel<<<1, 1, 0, stream>>>(edge, flags);

        node_kernel_t<false><<<nodeBlocks, 256, 0, stream>>>(
            h, W_src, b_src, W_dst, b_dst,
            Wa1_dst, ba1_dst, Wa2_dst, ba2_dst,
            nullptr, nullptr, out, nullptr, nullptr, N);

        edge_kernel_fused<<<edgeBlocks, 256, 0, stream>>>(
            edge, flags, h,
            W_src, b_src, W_dst, b_dst,
            Wa1_src, ba1_src, Wa2_src, ba2_src,
            out, E, N);
    }
}

// Round 7
// 517.031 us; speedup vs baseline: 8.0537x; 1.0782x over previous
//
#include <hip/hip_runtime.h>
#include <hip/hip_bf16.h>
#include <hip/hip_fp16.h>

#define NF   64
#define NH   8
#define ND   8
#define NHID 32

__device__ __forceinline__ float bf2f(unsigned short u) {
    union { unsigned int i; float f; } v; v.i = ((unsigned int)u) << 16; return v.f;
}
__device__ __forceinline__ unsigned short f2bf(float f) {
    __hip_bfloat16 b = __float2bfloat16(f);
    union { __hip_bfloat16 b; unsigned short u; } v; v.b = b; return v.u;
}
__device__ __forceinline__ void unpack8(uint4 u, float* o) {
    o[0] = __uint_as_float(u.x << 16); o[1] = __uint_as_float(u.x & 0xffff0000u);
    o[2] = __uint_as_float(u.y << 16); o[3] = __uint_as_float(u.y & 0xffff0000u);
    o[4] = __uint_as_float(u.z << 16); o[5] = __uint_as_float(u.z & 0xffff0000u);
    o[6] = __uint_as_float(u.w << 16); o[7] = __uint_as_float(u.w & 0xffff0000u);
}
__device__ __forceinline__ uint4 pack8(const float* f) {
    uint4 u;
    u.x = (unsigned)f2bf(f[0]) | ((unsigned)f2bf(f[1]) << 16);
    u.y = (unsigned)f2bf(f[2]) | ((unsigned)f2bf(f[3]) << 16);
    u.z = (unsigned)f2bf(f[4]) | ((unsigned)f2bf(f[5]) << 16);
    u.w = (unsigned)f2bf(f[6]) | ((unsigned)f2bf(f[7]) << 16);
    return u;
}
__device__ __forceinline__ float leaky(float x) { return x > 0.f ? x : 0.2f * x; }
__device__ __forceinline__ float sigmoidf(float x) { return 1.f / (1.f + __expf(-x)); }

__global__ void detect_kernel(const int* __restrict__ edge, int* __restrict__ flags) {
    if (threadIdx.x == 0 && blockIdx.x == 0) {
        int oddnz = 0;
        for (int i = 0; i < 32; i++) oddnz |= edge[2 * i + 1];
        flags[0] = (oddnz == 0) ? 1 : 0;
    }
}

__device__ __forceinline__ void load_edge(const int* __restrict__ edge, int e, int E,
                                          int wide, int& s, int& d) {
    if (wide) { s = edge[2 * e]; d = edge[2 * (E + e)]; }   // int64 storage
    else      { s = edge[e];     d = edge[E + e]; }          // int32 storage
}

// ---------------------------------------------------------------------------
// Node phase: stages g_src/g_dst (bf16), writes base a_dst*g_dst into fp32
// out (full overwrite), zeroes counts/cursor.
// ---------------------------------------------------------------------------
template <bool STORE_G>
__global__ __launch_bounds__(256) void node_kernel_t(
    const float* __restrict__ h,
    const float* __restrict__ W_src, const float* __restrict__ b_src,
    const float* __restrict__ W_dst, const float* __restrict__ b_dst,
    const float* __restrict__ Wa1, const float* __restrict__ ba1,
    const float* __restrict__ Wa2, const float* __restrict__ ba2,
    unsigned short* __restrict__ g_src_out, unsigned short* __restrict__ g_dst_out,
    float* __restrict__ out, int* __restrict__ counts, int* __restrict__ cursor, int N)
{
    __shared__ __align__(16) float sWs[NF * NF];
    __shared__ __align__(16) float sWd[NF * NF];
    __shared__ __align__(16) float sW1[NF * NHID];
    __shared__ __align__(16) float sW2[NHID * NH];
    __shared__ float sbs[NF], sbd[NF], sb1[NHID], sb2[NH];

    int tid = threadIdx.x;
    for (int i = tid; i < NF * NF; i += 256) { sWs[i] = W_src[i]; sWd[i] = W_dst[i]; }
    for (int i = tid; i < NF * NHID; i += 256) sW1[i] = Wa1[i];
    if (tid < NHID * NH) sW2[tid] = Wa2[tid];
    if (tid < NF) { sbs[tid] = b_src[tid]; sbd[tid] = b_dst[tid]; }
    if (tid < NHID) sb1[tid] = ba1[tid];
    if (tid < NH) sb2[tid] = ba2[tid];
    __syncthreads();

    int n = blockIdx.x * 256 + tid;
    if (n >= N) return;

    if (counts) { counts[n] = 0; cursor[n] = 0; }

    float hrow[NF];
    const float4* hv = (const float4*)(h + (size_t)n * NF);
    #pragma unroll
    for (int k = 0; k < 16; k++) {
        float4 u = hv[k];
        hrow[k * 4 + 0] = u.x; hrow[k * 4 + 1] = u.y;
        hrow[k * 4 + 2] = u.z; hrow[k * 4 + 3] = u.w;
    }

    float acc[NF];
    const float4* Wsv = (const float4*)sWs;
    const float4* Wdv = (const float4*)sWd;

    if (STORE_G) {
        #pragma unroll
        for (int j = 0; j < NF; j++) acc[j] = sbs[j];
        for (int i = 0; i < NF; i++) {
            float hi = hrow[i];
            #pragma unroll
            for (int jb = 0; jb < 16; jb++) {
                float4 w = Wsv[i * 16 + jb];
                acc[jb * 4 + 0] = fmaf(hi, w.x, acc[jb * 4 + 0]);
                acc[jb * 4 + 1] = fmaf(hi, w.y, acc[jb * 4 + 1]);
                acc[jb * 4 + 2] = fmaf(hi, w.z, acc[jb * 4 + 2]);
                acc[jb * 4 + 3] = fmaf(hi, w.w, acc[jb * 4 + 3]);
            }
        }
        uint4* gs = (uint4*)(g_src_out + (size_t)n * NF);
        #pragma unroll
        for (int k = 0; k < 8; k++) gs[k] = pack8(acc + k * 8);
    }

    #pragma unroll
    for (int j = 0; j < NF; j++) acc[j] = sbd[j];
    for (int i = 0; i < NF; i++) {
        float hi = hrow[i];
        #pragma unroll
        for (int jb = 0; jb < 16; jb++) {
            float4 w = Wdv[i * 16 + jb];
            acc[jb * 4 + 0] = fmaf(hi, w.x, acc[jb * 4 + 0]);
            acc[jb * 4 + 1] = fmaf(hi, w.y, acc[jb * 4 + 1]);
            acc[jb * 4 + 2] = fmaf(hi, w.z, acc[jb * 4 + 2]);
            acc[jb * 4 + 3] = fmaf(hi, w.w, acc[jb * 4 + 3]);
        }
    }
    if (STORE_G) {
        uint4* gd = (uint4*)(g_dst_out + (size_t)n * NF);
        #pragma unroll
        for (int k = 0; k < 8; k++) gd[k] = pack8(acc + k * 8);
    }

    float hid[NHID];
    #pragma unroll
    for (int j = 0; j < NHID; j++) hid[j] = sb1[j];
    const float4* W1v = (const float4*)sW1;
    for (int i = 0; i < NF; i++) {
        float xi = leaky(acc[i]);
        #pragma unroll
        for (int jb = 0; jb < 8; jb++) {
            float4 w = W1v[i * 8 + jb];
            hid[jb * 4 + 0] = fmaf(xi, w.x, hid[jb * 4 + 0]);
            hid[jb * 4 + 1] = fmaf(xi, w.y, hid[jb * 4 + 1]);
            hid[jb * 4 + 2] = fmaf(xi, w.z, hid[jb * 4 + 2]);
            hid[jb * 4 + 3] = fmaf(xi, w.w, hid[jb * 4 + 3]);
        }
    }
    float a[NH];
    #pragma unroll
    for (int j = 0; j < NH; j++) a[j] = sb2[j];
    #pragma unroll
    for (int k = 0; k < NHID; k++) {
        float xk = leaky(hid[k]);
        #pragma unroll
        for (int j = 0; j < NH; j++) a[j] = fmaf(xk, sW2[k * NH + j], a[j]);
    }
    #pragma unroll
    for (int j = 0; j < NH; j++) a[j] = sigmoidf(a[j]);

    float4* ap = (float4*)(out + (size_t)n * NF);
    #pragma unroll
    for (int k = 0; k < 16; k++) {
        int j = k * 4;
        ap[k] = make_float4(a[(j + 0) >> 3] * acc[j + 0],
                            a[(j + 1) >> 3] * acc[j + 1],
                            a[(j + 2) >> 3] * acc[j + 2],
                            a[(j + 3) >> 3] * acc[j + 3]);
    }
}

// ---------------------------------------------------------------------------
// Histogram of dst (sort-first pipeline).
// ---------------------------------------------------------------------------
__global__ __launch_bounds__(256) void hist_kernel(
    const int* __restrict__ edge, const int* __restrict__ flags,
    int* __restrict__ counts, int E, int N)
{
    int e = blockIdx.x * 256 + threadIdx.x;
    if (e >= E) return;
    int s, d;
    load_edge(edge, e, E, flags[0], s, d);
    if ((unsigned)s >= (unsigned)N || (unsigned)d >= (unsigned)N) return;
    atomicAdd(&counts[d], 1);
}

// ---------------------------------------------------------------------------
// Exclusive-scan machinery (counts -> CSR offsets), 2048 elems per block.
// ---------------------------------------------------------------------------
__global__ __launch_bounds__(256) void scan1_kernel(
    const int* __restrict__ counts, int* __restrict__ offsets,
    int* __restrict__ bsums, int N)
{
    __shared__ int lds[256];
    int tid = threadIdx.x;
    int base = blockIdx.x * 2048 + tid * 8;
    int v[8]; int s = 0;
    #pragma unroll
    for (int k = 0; k < 8; k++) { int idx = base + k; int t = (idx < N) ? counts[idx] : 0; v[k] = t; s += t; }
    lds[tid] = s;
    __syncthreads();
    for (int off = 1; off < 256; off <<= 1) {
        int y = (tid >= off) ? lds[tid - off] : 0;
        __syncthreads();
        lds[tid] += y;
        __syncthreads();
    }
    int run = lds[tid] - s;
    #pragma unroll
    for (int k = 0; k < 8; k++) { int idx = base + k; if (idx < N) offsets[idx] = run; run += v[k]; }
    if (tid == 255) bsums[blockIdx.x] = lds[255];
}

__global__ void scan2_kernel(int* __restrict__ bsums, int* __restrict__ offsets, int NB, int N) {
    if (threadIdx.x == 0 && blockIdx.x == 0) {
        int run = 0;
        for (int i = 0; i < NB; i++) { int t = bsums[i]; bsums[i] = run; run += t; }
        offsets[N] = run;
    }
}

__global__ __launch_bounds__(256) void scan3_kernel(
    int* __restrict__ offsets, const int* __restrict__ bsums, int N)
{
    int add = bsums[blockIdx.x];
    int base = blockIdx.x * 2048 + threadIdx.x * 8;
    #pragma unroll
    for (int k = 0; k < 8; k++) { int idx = base + k; if (idx < N) offsets[idx] += add; }
}

// ---------------------------------------------------------------------------
// Scatter (s,d) pairs into dst-sorted slots.
// ---------------------------------------------------------------------------
__global__ __launch_bounds__(256) void scatter_kernel(
    const int* __restrict__ edge, const int* __restrict__ flags,
    const int* __restrict__ offsets, int* __restrict__ cursor,
    uint2* __restrict__ sorted_sd, int E, int N)
{
    int e = blockIdx.x * 256 + threadIdx.x;
    if (e >= E) return;
    int s, d;
    load_edge(edge, e, E, flags[0], s, d);
    if ((unsigned)s >= (unsigned)N || (unsigned)d >= (unsigned)N) return;
    int pos = offsets[d] + atomicAdd(&cursor[d], 1);
    sorted_sd[pos] = make_uint2((unsigned)s, (unsigned)d);
}

// ---------------------------------------------------------------------------
// Edge MLP over SORTED slots: consecutive threads share d -> g_dst row hits
// L1/L2. Writes a (fp16x8, 16B) sequentially at the slot index.
// ---------------------------------------------------------------------------
__global__ __launch_bounds__(256) void edge_mlp_sorted_kernel(
    const uint2* __restrict__ sorted_sd, const int* __restrict__ total_p,
    const unsigned short* __restrict__ g_src, const unsigned short* __restrict__ g_dst,
    const float* __restrict__ Wa1, const float* __restrict__ ba1,
    const float* __restrict__ Wa2, const float* __restrict__ ba2,
    __half* __restrict__ a_sorted)
{
    __shared__ __align__(16) float sW1[NF * NHID];
    __shared__ __align__(16) float sW2[NHID * NH];
    __shared__ float sb1[NHID], sb2[NH];
    int tid = threadIdx.x;
    for (int i = tid; i < NF * NHID; i += 256) sW1[i] = Wa1[i];
    if (tid < NHID * NH) sW2[tid] = Wa2[tid];
    if (tid < NHID) sb1[tid] = ba1[tid];
    if (tid < NH) sb2[tid] = ba2[tid];
    __syncthreads();

    int i0 = blockIdx.x * 256 + tid;
    if (i0 >= *total_p) return;
    uint2 sd = sorted_sd[i0];

    float hid[NHID];
    #pragma unroll
    for (int j = 0; j < NHID; j++) hid[j] = sb1[j];

    const uint4* gs = (const uint4*)(g_src + (size_t)sd.x * NF);
    const uint4* gd = (const uint4*)(g_dst + (size_t)sd.y * NF);
    const float4* W1v = (const float4*)sW1;
    #pragma unroll
    for (int k = 0; k < 8; k++) {
        float a8[8], b8[8];
        unpack8(gs[k], a8);
        unpack8(gd[k], b8);
        #pragma unroll
        for (int t = 0; t < 8; t++) {
            int i = k * 8 + t;
            float x = leaky(a8[t] + b8[t]);
            #pragma unroll
            for (int jb = 0; jb < 8; jb++) {
                float4 w = W1v[i * 8 + jb];
                hid[jb * 4 + 0] = fmaf(x, w.x, hid[jb * 4 + 0]);
                hid[jb * 4 + 1] = fmaf(x, w.y, hid[jb * 4 + 1]);
                hid[jb * 4 + 2] = fmaf(x, w.z, hid[jb * 4 + 2]);
                hid[jb * 4 + 3] = fmaf(x, w.w, hid[jb * 4 + 3]);
            }
        }
    }

    float a[NH];
    #pragma unroll
    for (int j = 0; j < NH; j++) a[j] = sb2[j];
    #pragma unroll
    for (int k = 0; k < NHID; k++) {
        float xk = leaky(hid[k]);
        #pragma unroll
        for (int j = 0; j < NH; j++) a[j] = fmaf(xk, sW2[k * NH + j], a[j]);
    }

    union { __half h[8]; uint4 u; } pk;
    #pragma unroll
    for (int j = 0; j < NH; j++) pk.h[j] = __float2half(sigmoidf(a[j]));
    *(uint4*)(a_sorted + (size_t)i0 * NH) = pk.u;
}

// ---------------------------------------------------------------------------
// Aggregate: one wave per dst, lane = feature. Sequential a_sorted reads.
// ---------------------------------------------------------------------------
__global__ __launch_bounds__(256) void aggregate_kernel(
    const int* __restrict__ offsets, const uint2* __restrict__ sorted_sd,
    const __half* __restrict__ a_sorted, const unsigned short* __restrict__ g_src,
    float* __restrict__ out, int N)
{
    int d = blockIdx.x * 4 + (threadIdx.x >> 6);
    if (d >= N) return;
    int j = threadIdx.x & 63;
    int beg = offsets[d], end = offsets[d + 1];
    float acc = 0.f;
    for (int i = beg; i < end; i++) {
        unsigned s = sorted_sd[i].x;
        float av = __half2float(a_sorted[(size_t)i * NH + (j >> 3)]);
        float gv = bf2f(g_src[(size_t)s * NF + j]);
        acc = fmaf(av, gv, acc);
    }
    out[(size_t)d * NF + j] += acc;
}

// ---------------------------------------------------------------------------
// Fallbacks (small ws): R5 atomic edge kernel / fully fused.
// ---------------------------------------------------------------------------
__global__ __launch_bounds__(256) void edge_kernel(
    const int* __restrict__ edge, const int* __restrict__ flags,
    const unsigned short* __restrict__ g_src, const unsigned short* __restrict__ g_dst,
    const float* __restrict__ Wa1, const float* __restrict__ ba1,
    const float* __restrict__ Wa2, const float* __restrict__ ba2,
    float* __restrict__ out, int E, int N)
{
    __shared__ __align__(16) float sW1[NF * NHID];
    __shared__ __align__(16) float sW2[NHID * NH];
    __shared__ float sb1[NHID], sb2[NH];
    int tid = threadIdx.x;
    for (int i = tid; i < NF * NHID; i += 256) sW1[i] = Wa1[i];
    if (tid < NHID * NH) sW2[tid] = Wa2[tid];
    if (tid < NHID) sb1[tid] = ba1[tid];
    if (tid < NH) sb2[tid] = ba2[tid];
    __syncthreads();

    int e = blockIdx.x * 256 + tid;
    if (e >= E) return;
    int s, d;
    load_edge(edge, e, E, flags[0], s, d);
    if ((unsigned)s >= (unsigned)N || (unsigned)d >= (unsigned)N) return;

    float ms[NF];
    float hid[NHID];
    #pragma unroll
    for (int j = 0; j < NHID; j++) hid[j] = sb1[j];

    const uint4* gs = (const uint4*)(g_src + (size_t)s * NF);
    const uint4* gd = (const uint4*)(g_dst + (size_t)d * NF);
    #pragma unroll
    for (int k = 0; k < 8; k++) {
        float a8[8], b8[8];
        unpack8(gs[k], a8);
        unpack8(gd[k], b8);
        #pragma unroll
        for (int t = 0; t < 8; t++) {
            int i = k * 8 + t;
            ms[i] = a8[t];
            float x = leaky(a8[t] + b8[t]);
            #pragma unroll
            for (int j = 0; j < NHID; j++) hid[j] = fmaf(x, sW1[i * NHID + j], hid[j]);
        }
    }

    float a[NH];
    #pragma unroll
    for (int j = 0; j < NH; j++) a[j] = sb2[j];
    #pragma unroll
    for (int k = 0; k < NHID; k++) {
        float xk = leaky(hid[k]);
        #pragma unroll
        for (int j = 0; j < NH; j++) a[j] = fmaf(xk, sW2[k * NH + j], a[j]);
    }

    float* arow = out + (size_t)d * NF;
    #pragma unroll
    for (int hh = 0; hh < NH; hh++) {
        float ah = sigmoidf(a[hh]);
        #pragma unroll
        for (int dd = 0; dd < ND; dd++)
            unsafeAtomicAdd(arow + hh * ND + dd, ah * ms[hh * ND + dd]);
    }
}

__global__ __launch_bounds__(256) void edge_kernel_fused(
    const int* __restrict__ edge, const int* __restrict__ flags,
    const float* __restrict__ h,
    const float* __restrict__ W_src, const float* __restrict__ b_src,
    const float* __restrict__ W_dst, const float* __restrict__ b_dst,
    const float* __restrict__ Wa1, const float* __restrict__ ba1,
    const float* __restrict__ Wa2, const float* __restrict__ ba2,
    float* __restrict__ out, int E, int N)
{
    __shared__ __align__(16) float sWs[NF * NF];
    __shared__ __align__(16) float sWd[NF * NF];
    __shared__ __align__(16) float sW1[NF * NHID];
    __shared__ __align__(16) float sW2[NHID * NH];
    __shared__ float sbs[NF], sbd[NF], sb1[NHID], sb2[NH];
    int tid = threadIdx.x;
    for (int i = tid; i < NF * NF; i += 256) { sWs[i] = W_src[i]; sWd[i] = W_dst[i]; }
    for (int i = tid; i < NF * NHID; i += 256) sW1[i] = Wa1[i];
    if (tid < NHID * NH) sW2[tid] = Wa2[tid];
    if (tid < NF) { sbs[tid] = b_src[tid]; sbd[tid] = b_dst[tid]; }
    if (tid < NHID) sb1[tid] = ba1[tid];
    if (tid < NH) sb2[tid] = ba2[tid];
    __syncthreads();

    int e = blockIdx.x * 256 + tid;
    if (e >= E) return;
    int wide = flags ? flags[0] : 0;
    int s, d;
    load_edge(edge, e, E, wide, s, d);
    if ((unsigned)s >= (unsigned)N || (unsigned)d >= (unsigned)N) return;

    float gsr[NF], msg[NF];
    {
        float hrow[NF];
        #pragma unroll
        for (int i = 0; i < NF; i++) hrow[i] = h[(size_t)s * NF + i];
        #pragma unroll
        for (int j = 0; j < NF; j++) gsr[j] = sbs[j];
        for (int i = 0; i < NF; i++) {
            float hi = hrow[i];
            #pragma unroll
            for (int j = 0; j < NF; j++) gsr[j] = fmaf(hi, sWs[i * NF + j], gsr[j]);
        }
    }
    #pragma unroll
    for (int j = 0; j < NF; j++) msg[j] = gsr[j] + sbd[j];
    for (int i = 0; i < NF; i++) {
        float hi = h[(size_t)d * NF + i];
        #pragma unroll
        for (int j = 0; j < NF; j++) msg[j] = fmaf(hi, sWd[i * NF + j], msg[j]);
    }

    float hid[NHID];
    #pragma unroll
    for (int j = 0; j < NHID; j++) hid[j] = sb1[j];
    for (int i = 0; i < NF; i++) {
        float x = leaky(msg[i]);
        #pragma unroll
        for (int j = 0; j < NHID; j++) hid[j] = fmaf(x, sW1[i * NHID + j], hid[j]);
    }
    float a[NH];
    #pragma unroll
    for (int j = 0; j < NH; j++) a[j] = sb2[j];
    #pragma unroll
    for (int k = 0; k < NHID; k++) {
        float xk = leaky(hid[k]);
        #pragma unroll
        for (int j = 0; j < NH; j++) a[j] = fmaf(xk, sW2[k * NH + j], a[j]);
    }

    float* arow = out + (size_t)d * NF;
    #pragma unroll
    for (int hh = 0; hh < NH; hh++) {
        float ah = sigmoidf(a[hh]);
        #pragma unroll
        for (int dd = 0; dd < ND; dd++)
            unsafeAtomicAdd(arow + hh * ND + dd, ah * gsr[hh * ND + dd]);
    }
}

static inline size_t al256(size_t x) { return (x + 255) & ~(size_t)255; }

extern "C" void kernel_launch(void* const* d_in, const int* in_sizes, int n_in,
                              void* d_out, int out_size, void* d_ws, size_t ws_size,
                              hipStream_t stream) {
    const float* h       = (const float*)d_in[0];
    const float* W_src   = (const float*)d_in[1];
    const float* b_src   = (const float*)d_in[2];
    const float* W_dst   = (const float*)d_in[3];
    const float* b_dst   = (const float*)d_in[4];
    const float* Wa1_src = (const float*)d_in[5];
    const float* ba1_src = (const float*)d_in[6];
    const float* Wa2_src = (const float*)d_in[7];
    const float* ba2_src = (const float*)d_in[8];
    const float* Wa1_dst = (const float*)d_in[9];
    const float* ba1_dst = (const float*)d_in[10];
    const float* Wa2_dst = (const float*)d_in[11];
    const float* ba2_dst = (const float*)d_in[12];
    const int* edge = (const int*)d_in[13];

    int N = in_sizes[0] / NF;
    int E = in_sizes[13] / 2;
    float* out = (float*)d_out;

    int nodeBlocks = (N + 255) / 256;
    int edgeBlocks = (E + 255) / 256;
    int NB1 = (N + 2047) / 2048;

    // ws layout (sort path)
    size_t o_flags  = 0;
    size_t o_gsrc   = al256(o_flags + 256);
    size_t o_gdst   = al256(o_gsrc + (size_t)N * NF * 2);
    size_t o_asort  = al256(o_gdst + (size_t)N * NF * 2);
    size_t o_counts = al256(o_asort + (size_t)E * NH * 2);
    size_t o_offs   = al256(o_counts + (size_t)N * 4);
    size_t o_cursor = al256(o_offs + ((size_t)N + 1) * 4);
    size_t o_bsums  = al256(o_cursor + (size_t)N * 4);
    size_t o_sorted = al256(o_bsums + (size_t)NB1 * 4);
    size_t need     = o_sorted + (size_t)E * 8;

    size_t gB = (size_t)N * NF * 2;

    if (ws_size >= need) {
        // ---------------- Sort-first path -----------------------------------
        char* w = (char*)d_ws;
        int*            flags   = (int*)(w + o_flags);
        unsigned short* g_src   = (unsigned short*)(w + o_gsrc);
        unsigned short* g_dst   = (unsigned short*)(w + o_gdst);
        __half*         a_sort  = (__half*)(w + o_asort);
        int*            counts  = (int*)(w + o_counts);
        int*            offsets = (int*)(w + o_offs);
        int*            cursor  = (int*)(w + o_cursor);
        int*            bsums   = (int*)(w + o_bsums);
        uint2*          sorted  = (uint2*)(w + o_sorted);

        detect_kernel<<<1, 1, 0, stream>>>(edge, flags);

        node_kernel_t<true><<<nodeBlocks, 256, 0, stream>>>(
            h, W_src, b_src, W_dst, b_dst,
            Wa1_dst, ba1_dst, Wa2_dst, ba2_dst,
            g_src, g_dst, out, counts, cursor, N);

        hist_kernel<<<edgeBlocks, 256, 0, stream>>>(edge, flags, counts, E, N);

        scan1_kernel<<<NB1, 256, 0, stream>>>(counts, offsets, bsums, N);
        scan2_kernel<<<1, 1, 0, stream>>>(bsums, offsets, NB1, N);
        scan3_kernel<<<NB1, 256, 0, stream>>>(offsets, bsums, N);

        scatter_kernel<<<edgeBlocks, 256, 0, stream>>>(
            edge, flags, offsets, cursor, sorted, E, N);

        edge_mlp_sorted_kernel<<<edgeBlocks, 256, 0, stream>>>(
            sorted, offsets + N, g_src, g_dst,
            Wa1_src, ba1_src, Wa2_src, ba2_src, a_sort);

        aggregate_kernel<<<(N + 3) / 4, 256, 0, stream>>>(
            offsets, sorted, a_sort, g_src, out, N);
    } else if (ws_size >= 256 + 2 * gB) {
        // ---------------- R5 known-good path --------------------------------
        int* flags = (int*)d_ws;
        unsigned short* g_src = (unsigned short*)((char*)d_ws + 256);
        unsigned short* g_dst = g_src + (size_t)N * NF;

        detect_kernel<<<1, 1, 0, stream>>>(edge, flags);

        node_kernel_t<true><<<nodeBlocks, 256, 0, stream>>>(
            h, W_src, b_src, W_dst, b_dst,
            Wa1_dst, ba1_dst, Wa2_dst, ba2_dst,
            g_src, g_dst, out, nullptr, nullptr, N);

        edge_kernel<<<edgeBlocks, 256, 0, stream>>>(
            edge, flags, g_src, g_dst,
            Wa1_src, ba1_src, Wa2_src, ba2_src,
            out, E, N);
    } else {
        // ---------------- zero-ws fused fallback ----------------------------
        int* flags = (ws_size >= 256) ? (int*)d_ws : nullptr;
        if (flags) detect_kernel<<<1, 1, 0, stream>>>(edge, flags);

        node_kernel_t<false><<<nodeBlocks, 256, 0, stream>>>(
            h, W_src, b_src, W_dst, b_dst,
            Wa1_dst, ba1_dst, Wa2_dst, ba2_dst,
            nullptr, nullptr, out, nullptr, nullptr, N);

        edge_kernel_fused<<<edgeBlocks, 256, 0, stream>>>(
            edge, flags, h,
            W_src, b_src, W_dst, b_dst,
            Wa1_src, ba1_src, Wa2_src, ba2_src,
            out, E, N);
    }
}